// Round 14
// baseline (129.727 us; speedup 1.0000x reference)
//
#include <hip/hip_runtime.h>

#define NA 150381
#define NC 90
#define MDET 100
#define STHR 0.996f
#define T2 0.99997f   // second-stage threshold: E[#>T2]~406, gc in [105,1024] @ >15 sigma
#define NTHR 0.5f
#define IMGF 896.0f
#define NBF 1056      // fallback histogram bins ((bits-SB)>>6 over [0.996,1))
#define KCAP 1024     // gsel capacity
#define NW 16         // KCAP/64 kept-words
#define K2CAP 2048    // fallback list capacity

typedef unsigned long long u64;

__device__ __forceinline__ int binf(unsigned bits, unsigned SB) {
  int b = (int)((bits - SB) >> 6);
  return b < NBF - 1 ? b : NBF - 1;
}
// single source of truth for box decode -> bit-identical everywhere
__device__ __forceinline__ float4 decode_box(float4 a, float4 r) {
  float cxa = (a.x + a.z) * 0.5f, cya = (a.y + a.w) * 0.5f;
  float wa = a.z - a.x, ha = a.w - a.y;
  float w = expf(r.w) * wa, h = expf(r.z) * ha;
  float cy = r.x * ha + cya, cx = r.y * wa + cxa;
  float4 b;
  b.x = fminf(fmaxf(cx - w * 0.5f, 0.f), IMGF);
  b.y = fminf(fmaxf(cy - h * 0.5f, 0.f), IMGF);
  b.z = fminf(fmaxf(cx + w * 0.5f, 0.f), IMGF);
  b.w = fminf(fmaxf(cy + h * 0.5f, 0.f), IMGF);
  return b;
}
__device__ __forceinline__ bool iou_gt(float x1, float y1, float x2, float y2, float a1,
                                       float u1, float v1, float u2, float v2, float a2) {
  float ix1 = fmaxf(x1, u1), iy1 = fmaxf(y1, v1);
  float ix2 = fminf(x2, u2), iy2 = fminf(y2, v2);
  float iw = fmaxf(ix2 - ix1, 0.f), ih = fmaxf(iy2 - iy1, 0.f);
  float inter = iw * ih;
  float uni = a1 + a2 - inter;
  return inter / fmaxf(uni, 1e-9f) > NTHR;
}
// key = score_bits<<32 | (0xFFFFFFFF - (c<<18 | anchor)): u64-desc order ==
// (score desc, class asc, anchor asc) == reference flat-index tie order.
__device__ __forceinline__ u64 make_key(unsigned bits, int c, int i) {
  return ((u64)bits << 32) |
         (u64)(0xFFFFFFFFu - (((unsigned)c << 18) | (unsigned)i));
}

// ---------------- zero the two counters ----------------
__global__ void k_zero(int* __restrict__ gcnt, int* __restrict__ totcnt) {
  if (threadIdx.x == 0) { *gcnt = 0; *totcnt = 0; }
}

// ---------------- stream 54MB: count >STHR, append >T2 to gsel ----------------
__global__ void k_collect(const float4* __restrict__ cls4, u64* __restrict__ gsel,
                          int* __restrict__ gcnt, int* __restrict__ totcnt) {
  const int total = NA * NC;
  const int nv4 = total >> 2;
  const int stride = gridDim.x * blockDim.x;
  int tcnt = 0;
  for (int q = blockIdx.x * blockDim.x + threadIdx.x; q < nv4; q += stride) {
    float4 v4 = cls4[q];
    float vv[4] = {v4.x, v4.y, v4.z, v4.w};
    #pragma unroll
    for (int e = 0; e < 4; ++e) {
      float v = vv[e];
      if (v > STHR) {
        ++tcnt;
        if (v > T2) {
          int f = q * 4 + e;
          int p = atomicAdd(gcnt, 1);
          if (p < KCAP) gsel[p] = make_key(__float_as_uint(v), f % NC, f / NC);
        }
      }
    }
  }
  int g = blockIdx.x * blockDim.x + threadIdx.x;
  if (g < total - nv4 * 4) {
    int f = nv4 * 4 + g;
    float v = ((const float*)cls4)[f];
    if (v > STHR) {
      ++tcnt;
      if (v > T2) {
        int p = atomicAdd(gcnt, 1);
        if (p < KCAP) gsel[p] = make_key(__float_as_uint(v), f % NC, f / NC);
      }
    }
  }
  if (tcnt) atomicAdd(totcnt, tcnt);
}

// ---------------- one block: sort gsel, class-bitmap NMS fixpoint, output 100 ----
__global__ __launch_bounds__(1024) void k_top(const int* __restrict__ gcnt,
                                              const int* __restrict__ totcnt,
                                              const u64* __restrict__ gsel,
                                              const float4* __restrict__ cls4,
                                              const float4* __restrict__ anc,
                                              const float4* __restrict__ reg,
                                              const float* __restrict__ ta,
                                              const float* __restrict__ td,
                                              const float* __restrict__ rot,
                                              float* __restrict__ out) {
  extern __shared__ u64 dyn[];
  u64* skey = dyn;                                     // [2048] 16 KB
  float* bx1 = (float*)(dyn + 2048);                   // 5 x [2048] 40 KB
  float* by1 = bx1 + 2048; float* bx2 = by1 + 2048;
  float* by2 = bx2 + 2048; float* ar  = by2 + 2048;
  unsigned short* scls = (unsigned short*)(ar + 2048); // [2048] 4 KB
  unsigned char*  alv  = (unsigned char*)(scls + 2048);// [2048] 2 KB
  u64* classbit = (u64*)(alv + 2048);                  // [NC][NW] 11.25 KB
  unsigned* fhist = (unsigned*)classbit;               // fallback overlay (1056 u32)
  __shared__ u64 sK[NW];
  __shared__ int keptlist[MDET];
  __shared__ int cls_seen[NC];
  __shared__ int wsum[16], wsuf[16];
  __shared__ int s_chg, s_cnt2, s_B2, s_kept;

  const int tid = threadIdx.x;
  const int wv = tid >> 6, lane = tid & 63;
  const unsigned SB = __float_as_uint(STHR);

  if (tid < NC) cls_seen[tid] = 0;
  if (tid < MDET) keptlist[tid] = -1;
  if (tid == 0) { s_cnt2 = 0; s_kept = 0; }
  for (int t = tid; t < NC * NW; t += 1024) classbit[t] = 0ULL;
  __syncthreads();
  const int total = *totcnt;
  const int gc = *gcnt;
  bool fallback = (gc > KCAP);

  if (!fallback) {
    // ---- element/thread bitonic sort of 1024 (shfl j<64, LDS j>=64) ----
    u64 v = (tid < gc) ? gsel[tid] : 0ULL;
    for (int k = 2; k <= 1024; k <<= 1) {
      for (int j = k >> 1; j > 0; j >>= 1) {
        u64 p;
        if (j >= 64) {
          __syncthreads(); skey[tid] = v; __syncthreads();
          p = skey[tid ^ j];
        } else {
          p = __shfl_xor(v, j, 64);
        }
        u64 mx = (v >= p) ? v : p, mn = (v >= p) ? p : v;
        bool takeMax = (((tid & k) == 0) != ((tid & j) != 0));
        v = takeMax ? mx : mn;
      }
    }
    __syncthreads();
    skey[tid] = v;

    // ---- decode + stage boxes/class + class bitmap ----
    float mx1 = 0, my1 = 0, mx2 = 0, my2 = 0, mar = 0;
    int myc = -1;
    if (tid < gc) {
      unsigned u = 0xFFFFFFFFu - (unsigned)v;
      myc = (int)(u >> 18);
      unsigned aidx = u & 0x3FFFFu;
      float4 b = decode_box(anc[aidx], reg[aidx]);
      mx1 = b.x; my1 = b.y; mx2 = b.z; my2 = b.w;
      mar = (b.z - b.x) * (b.w - b.y);
      bx1[tid] = b.x; by1[tid] = b.y; bx2[tid] = b.z; by2[tid] = b.w;
      ar[tid] = mar; scls[tid] = (unsigned short)myc;
      atomicOr(&classbit[myc * NW + (tid >> 6)], 1ULL << (tid & 63));
    }
    __syncthreads();

    // ---- per-thread suppressor bitmask: same-class predecessors with IoU>thr ----
    u64 sup[NW];
    #pragma unroll
    for (int w = 0; w < NW; ++w) sup[w] = 0ULL;
    if (tid < gc) {
      const int tw = tid >> 6;
      for (int w = 0; w <= tw; ++w) {
        u64 m = classbit[myc * NW + w];
        if (w == tw) m &= (tid & 63) ? ((1ULL << (tid & 63)) - 1ULL) : 0ULL;
        u64 acc = 0ULL;
        while (m) {
          int b = __ffsll(m) - 1;
          m &= m - 1ULL;
          int s = (w << 6) + b;
          if (iou_gt(mx1, my1, mx2, my2, mar, bx1[s], by1[s], bx2[s], by2[s], ar[s]))
            acc |= 1ULL << b;
        }
        sup[w] = acc;
      }
    }

    // ---- Jacobi fixpoint on kept bits (unique fixpoint == greedy keep set) ----
    if (tid < NW) {
      int lo = tid << 6;
      sK[tid] = (gc <= lo) ? 0ULL : ((gc - lo >= 64) ? ~0ULL : ((1ULL << (gc - lo)) - 1));
    }
    __syncthreads();
    for (int it = 0; it < KCAP; ++it) {
      if (tid == 0) s_chg = 0;
      __syncthreads();
      bool alive = (tid < gc);
      if (alive) {
        u64 r = 0ULL;
        #pragma unroll
        for (int w = 0; w < NW; ++w) r |= sup[w] & sK[w];
        alive = (r == 0ULL);
      }
      u64 nw = __ballot(alive);
      __syncthreads();                       // all sK reads complete before writes
      if (lane == 0 && nw != sK[wv]) { sK[wv] = nw; s_chg = 1; }
      __syncthreads();
      if (!s_chg) break;
    }
    if (tid == 0) {
      int kt = 0;
      for (int w = 0; w < NW; ++w) kt += __popcll(sK[w]);
      s_kept = kt;
    }
    __syncthreads();
    if (s_kept >= MDET || gc >= total) {
      if (tid < gc && ((sK[wv] >> lane) & 1ULL)) {
        int slot = __popcll(sK[wv] & ((1ULL << lane) - 1ULL));
        for (int w = 0; w < wv; ++w) slot += __popcll(sK[w]);
        if (slot < MDET) keptlist[slot] = tid;
      }
    } else {
      fallback = true;                       // need deeper list (never on this data)
    }
    __syncthreads();
  }

  if (fallback) {
    // ==== exact fallback: rebuild from classification (slow, never taken) ====
    const int totalNC = NA * NC;
    const int nv4 = totalNC >> 2;
    for (int t = tid; t < NBF; t += 1024) fhist[t] = 0u;
    __syncthreads();
    for (int q = tid; q < nv4; q += 1024) {
      float4 v4 = cls4[q];
      float vv[4] = {v4.x, v4.y, v4.z, v4.w};
      #pragma unroll
      for (int e = 0; e < 4; ++e)
        if (vv[e] > STHR) atomicAdd(&fhist[binf(__float_as_uint(vv[e]), SB)], 1u);
    }
    if (tid < totalNC - nv4 * 4) {
      float v = ((const float*)cls4)[nv4 * 4 + tid];
      if (v > STHR) atomicAdd(&fhist[binf(__float_as_uint(v), SB)], 1u);
    }
    __syncthreads();
    // threshold bin: strictly-above prefix with count <= K2CAP
    {
      int b0 = 2 * tid;
      int h0 = (b0 < NBF) ? (int)fhist[b0] : 0;
      int h1 = (b0 + 1 < NBF) ? (int)fhist[b0 + 1] : 0;
      int s = h0 + h1;
      int ss = s;
      for (int d = 1; d < 64; d <<= 1) {
        int v = __shfl_down(ss, d);
        if (lane + d < 64) ss += v;
      }
      if (lane == 0) wsum[wv] = ss;
      if (tid == 0) s_B2 = 0;
      __syncthreads();
      if (tid < 16) {
        int x = wsum[tid];
        for (int d = 1; d < 16; d <<= 1) {
          int v = __shfl_down(x, d);
          if (tid + d < 16) x += v;
        }
        wsuf[tid] = x;
      }
      __syncthreads();
      int suff = ss + ((wv < 15) ? wsuf[wv + 1] : 0);
      int suffn = suff - s;
      if (suff >= K2CAP && suffn < K2CAP) {
        int Bx = (suffn + h1 >= K2CAP) ? (b0 + 1) : b0;
        s_B2 = Bx + 1;
      }
      __syncthreads();
    }
    const int B2 = s_B2;
    for (int q = tid; q < nv4; q += 1024) {
      float4 v4 = cls4[q];
      float vv[4] = {v4.x, v4.y, v4.z, v4.w};
      #pragma unroll
      for (int e = 0; e < 4; ++e) {
        float v = vv[e];
        if (v > STHR && binf(__float_as_uint(v), SB) >= B2) {
          int f = q * 4 + e;
          int p = atomicAdd(&s_cnt2, 1);
          if (p < K2CAP) skey[p] = make_key(__float_as_uint(v), f % NC, f / NC);
        }
      }
    }
    if (tid < totalNC - nv4 * 4) {
      int f = nv4 * 4 + tid;
      float v = ((const float*)cls4)[f];
      if (v > STHR && binf(__float_as_uint(v), SB) >= B2) {
        int p = atomicAdd(&s_cnt2, 1);
        if (p < K2CAP) skey[p] = make_key(__float_as_uint(v), f % NC, f / NC);
      }
    }
    __syncthreads();
    const int gc2 = min(s_cnt2, K2CAP);
    int NS2 = 2;
    while (NS2 < gc2) NS2 <<= 1;
    for (int t = tid; t < NS2; t += 1024) if (t >= gc2) skey[t] = 0ULL;
    for (int k = 2; k <= NS2; k <<= 1) {
      for (int j = k >> 1; j > 0; j >>= 1) {
        __syncthreads();
        for (int i = tid; i < NS2; i += 1024) {
          int ixj = i ^ j;
          if (ixj > i) {
            u64 x = skey[i], y = skey[ixj];
            if (((i & k) == 0) ? (x < y) : (x > y)) { skey[i] = y; skey[ixj] = x; }
          }
        }
      }
    }
    __syncthreads();
    for (int t = tid; t < gc2; t += 1024) {
      u64 k = skey[t];
      unsigned u = 0xFFFFFFFFu - (unsigned)k;
      unsigned aidx = u & 0x3FFFFu;
      float4 b = decode_box(anc[aidx], reg[aidx]);
      bx1[t] = b.x; by1[t] = b.y; bx2[t] = b.z; by2[t] = b.w;
      ar[t] = (b.z - b.x) * (b.w - b.y);
      scls[t] = (unsigned short)(u >> 18);
      alv[t] = 1;
    }
    __syncthreads();
    if (tid < 64) {                          // exact wave-serial greedy, cap MDET
      int kept = 0;
      for (int i = 0; i < gc2 && kept < MDET; ++i) {
        int ci = (int)scls[i];
        int skip = 0;
        if (tid == 0) {                      // per-class PRE_K rank guard
          skip = (cls_seen[ci] >= 1024) ? 1 : 0;
          cls_seen[ci]++;
        }
        skip = __shfl(skip, 0);
        if (skip || !alv[i]) continue;
        if (tid == 0) keptlist[kept] = i;
        float x1 = bx1[i], y1 = by1[i], x2 = bx2[i], y2 = by2[i], ai = ar[i];
        for (int j = i + 1 + tid; j < gc2; j += 64)
          if (alv[j] && (int)scls[j] == ci &&
              iou_gt(x1, y1, x2, y2, ai, bx1[j], by1[j], bx2[j], by2[j], ar[j]))
            alv[j] = 0;
        ++kept;
      }
    }
    __syncthreads();
  }

  // ---- output: first MDET kept in sorted order (== global top-100 kept) ----
  if (tid < MDET) {
    int r = keptlist[tid];
    bool ok = (r >= 0);
    float b0 = -1.f, b1 = -1.f, b2 = -1.f, b3 = -1.f;
    float r0 = -1.f, r1 = -1.f, r2 = -1.f;
    float t0 = -1.f, t1 = -1.f, t2 = -1.f;
    float sc = -1.f, lab = -1.f;
    if (ok) {
      u64 key = skey[r];
      sc = __uint_as_float((unsigned)(key >> 32));
      unsigned u = 0xFFFFFFFFu - (unsigned)key;
      int c = (int)(u >> 18);
      unsigned aidx = u & 0x3FFFFu;
      float4 bb = decode_box(anc[aidx], reg[aidx]);
      b0 = bb.x; b1 = bb.y; b2 = bb.z; b3 = bb.w;
      lab = (float)c;
      r0 = rot[aidx * 3 + 0]; r1 = rot[aidx * 3 + 1]; r2 = rot[aidx * 3 + 2];
      float st = ta[aidx * 3 + 2];
      t0 = ta[aidx * 3 + 0] + td[aidx * 3 + 0] * st;
      t1 = ta[aidx * 3 + 1] + td[aidx * 3 + 1] * st;
      t2 = td[aidx * 3 + 2];
    }
    out[tid * 4 + 0] = b0; out[tid * 4 + 1] = b1;
    out[tid * 4 + 2] = b2; out[tid * 4 + 3] = b3;
    out[400 + tid] = sc;
    out[500 + tid] = lab;
    out[600 + tid * 3 + 0] = r0; out[600 + tid * 3 + 1] = r1; out[600 + tid * 3 + 2] = r2;
    out[900 + tid * 3 + 0] = t0; out[900 + tid * 3 + 1] = t1; out[900 + tid * 3 + 2] = t2;
  }
}

extern "C" void kernel_launch(void* const* d_in, const int* in_sizes, int n_in,
                              void* d_out, int out_size, void* d_ws, size_t ws_size,
                              hipStream_t stream) {
  const float* anchors        = (const float*)d_in[0];
  const float* regression     = (const float*)d_in[1];
  const float* classification = (const float*)d_in[2];
  const float* rotation       = (const float*)d_in[3];
  const float* tanch          = (const float*)d_in[4];
  const float* tdelta         = (const float*)d_in[5];
  float* out = (float*)d_out;

  char* ws = (char*)d_ws;
  size_t off = 0;
  auto alloc = [&](size_t bytes) -> void* {
    void* p = ws + off;
    off += (bytes + 255) & ~(size_t)255;
    return p;
  };
  int* gcnt   = (int*)alloc(4);
  int* totcnt = (int*)alloc(4);
  u64* gsel   = (u64*)alloc((size_t)KCAP * 8);

  k_zero<<<1, 64, 0, stream>>>(gcnt, totcnt);
  k_collect<<<2048, 256, 0, stream>>>((const float4*)classification, gsel, gcnt, totcnt);

  // dyn: skey 16K + boxes 40K + scls 4K + alv 2K + classbit 11.25K = ~73.3 KB
  hipFuncSetAttribute(reinterpret_cast<const void*>(k_top),
                      hipFuncAttributeMaxDynamicSharedMemorySize, 75776);
  k_top<<<1, 1024, 75776, stream>>>(gcnt, totcnt, gsel,
                                    (const float4*)classification,
                                    (const float4*)anchors, (const float4*)regression,
                                    tanch, tdelta, rotation, out);
}

// Round 15
// 60.610 us; speedup vs baseline: 2.1404x; 2.1404x over previous
//
#include <hip/hip_runtime.h>

#define NA 150381
#define NC 90
#define MDET 100
#define STHR 0.996f
#define T2 0.99997f   // second-stage threshold: E[#>T2]~406, gc in [105,1024] @ >15 sigma
#define NTHR 0.5f
#define IMGF 896.0f
#define NBF 1056      // fallback histogram bins ((bits-SB)>>6 over [0.996,1))
#define KCAP 1024     // gsel capacity
#define NW 16         // KCAP/64 kept-words
#define K2CAP 2048    // fallback list capacity

typedef unsigned long long u64;

__device__ __forceinline__ int binf(unsigned bits, unsigned SB) {
  int b = (int)((bits - SB) >> 6);
  return b < NBF - 1 ? b : NBF - 1;
}
// single source of truth for box decode -> bit-identical everywhere
__device__ __forceinline__ float4 decode_box(float4 a, float4 r) {
  float cxa = (a.x + a.z) * 0.5f, cya = (a.y + a.w) * 0.5f;
  float wa = a.z - a.x, ha = a.w - a.y;
  float w = expf(r.w) * wa, h = expf(r.z) * ha;
  float cy = r.x * ha + cya, cx = r.y * wa + cxa;
  float4 b;
  b.x = fminf(fmaxf(cx - w * 0.5f, 0.f), IMGF);
  b.y = fminf(fmaxf(cy - h * 0.5f, 0.f), IMGF);
  b.z = fminf(fmaxf(cx + w * 0.5f, 0.f), IMGF);
  b.w = fminf(fmaxf(cy + h * 0.5f, 0.f), IMGF);
  return b;
}
__device__ __forceinline__ bool iou_gt(float x1, float y1, float x2, float y2, float a1,
                                       float u1, float v1, float u2, float v2, float a2) {
  float ix1 = fmaxf(x1, u1), iy1 = fmaxf(y1, v1);
  float ix2 = fminf(x2, u2), iy2 = fminf(y2, v2);
  float iw = fmaxf(ix2 - ix1, 0.f), ih = fmaxf(iy2 - iy1, 0.f);
  float inter = iw * ih;
  float uni = a1 + a2 - inter;
  return inter / fmaxf(uni, 1e-9f) > NTHR;
}
// key = score_bits<<32 | (0xFFFFFFFF - (c<<18 | anchor)): u64-desc order ==
// (score desc, class asc, anchor asc) == reference flat-index tie order.
__device__ __forceinline__ u64 make_key(unsigned bits, int c, int i) {
  return ((u64)bits << 32) |
         (u64)(0xFFFFFFFFu - (((unsigned)c << 18) | (unsigned)i));
}

// ---------------- zero the two counters ----------------
__global__ void k_zero(int* __restrict__ gcnt, int* __restrict__ totcnt) {
  if (threadIdx.x == 0) { *gcnt = 0; *totcnt = 0; }
}

// ---------------- stream 54MB: count >STHR (block-reduced), append >T2 ----------
__global__ void k_collect(const float4* __restrict__ cls4, u64* __restrict__ gsel,
                          int* __restrict__ gcnt, int* __restrict__ totcnt) {
  __shared__ int wpart[4];                   // 256 threads = 4 waves
  const int total = NA * NC;
  const int nv4 = total >> 2;
  const int stride = gridDim.x * blockDim.x;
  int tcnt = 0;
  for (int q = blockIdx.x * blockDim.x + threadIdx.x; q < nv4; q += stride) {
    float4 v4 = cls4[q];
    float vv[4] = {v4.x, v4.y, v4.z, v4.w};
    #pragma unroll
    for (int e = 0; e < 4; ++e) {
      float v = vv[e];
      if (v > STHR) {
        ++tcnt;
        if (v > T2) {
          int f = q * 4 + e;
          int p = atomicAdd(gcnt, 1);
          if (p < KCAP) gsel[p] = make_key(__float_as_uint(v), f % NC, f / NC);
        }
      }
    }
  }
  int g = blockIdx.x * blockDim.x + threadIdx.x;
  if (g < total - nv4 * 4) {
    int f = nv4 * 4 + g;
    float v = ((const float*)cls4)[f];
    if (v > STHR) {
      ++tcnt;
      if (v > T2) {
        int p = atomicAdd(gcnt, 1);
        if (p < KCAP) gsel[p] = make_key(__float_as_uint(v), f % NC, f / NC);
      }
    }
  }
  // hierarchical reduce: wave shfl -> LDS -> ONE atomic per block (G12)
  for (int d = 32; d > 0; d >>= 1) tcnt += __shfl_down(tcnt, d);
  const int lane = threadIdx.x & 63, wv = threadIdx.x >> 6;
  if (lane == 0) wpart[wv] = tcnt;
  __syncthreads();
  if (threadIdx.x == 0) {
    int s = wpart[0] + wpart[1] + wpart[2] + wpart[3];
    if (s) atomicAdd(totcnt, s);
  }
}

// ---------------- one block: sort gsel, class-bitmap NMS fixpoint, output 100 ----
__global__ __launch_bounds__(1024) void k_top(const int* __restrict__ gcnt,
                                              const int* __restrict__ totcnt,
                                              const u64* __restrict__ gsel,
                                              const float4* __restrict__ cls4,
                                              const float4* __restrict__ anc,
                                              const float4* __restrict__ reg,
                                              const float* __restrict__ ta,
                                              const float* __restrict__ td,
                                              const float* __restrict__ rot,
                                              float* __restrict__ out) {
  extern __shared__ u64 dyn[];
  u64* skey = dyn;                                     // [2048] 16 KB
  float* bx1 = (float*)(dyn + 2048);                   // 5 x [2048] 40 KB
  float* by1 = bx1 + 2048; float* bx2 = by1 + 2048;
  float* by2 = bx2 + 2048; float* ar  = by2 + 2048;
  unsigned short* scls = (unsigned short*)(ar + 2048); // [2048] 4 KB
  unsigned char*  alv  = (unsigned char*)(scls + 2048);// [2048] 2 KB
  u64* classbit = (u64*)(alv + 2048);                  // [NC][NW] 11.25 KB
  unsigned* fhist = (unsigned*)classbit;               // fallback overlay (1056 u32)
  __shared__ u64 sK[NW];
  __shared__ int keptlist[MDET];
  __shared__ int cls_seen[NC];
  __shared__ int wsum[16], wsuf[16];
  __shared__ int s_chg, s_cnt2, s_B2, s_kept;

  const int tid = threadIdx.x;
  const int wv = tid >> 6, lane = tid & 63;
  const unsigned SB = __float_as_uint(STHR);

  if (tid < NC) cls_seen[tid] = 0;
  if (tid < MDET) keptlist[tid] = -1;
  if (tid == 0) { s_cnt2 = 0; s_kept = 0; }
  for (int t = tid; t < NC * NW; t += 1024) classbit[t] = 0ULL;
  __syncthreads();
  const int total = *totcnt;
  const int gc = *gcnt;
  bool fallback = (gc > KCAP);

  if (!fallback) {
    // ---- element/thread bitonic sort of 1024 (shfl j<64, LDS j>=64) ----
    u64 v = (tid < gc) ? gsel[tid] : 0ULL;
    for (int k = 2; k <= 1024; k <<= 1) {
      for (int j = k >> 1; j > 0; j >>= 1) {
        u64 p;
        if (j >= 64) {
          __syncthreads(); skey[tid] = v; __syncthreads();
          p = skey[tid ^ j];
        } else {
          p = __shfl_xor(v, j, 64);
        }
        u64 mx = (v >= p) ? v : p, mn = (v >= p) ? p : v;
        bool takeMax = (((tid & k) == 0) != ((tid & j) != 0));
        v = takeMax ? mx : mn;
      }
    }
    __syncthreads();
    skey[tid] = v;

    // ---- decode + stage boxes/class + class bitmap ----
    float mx1 = 0, my1 = 0, mx2 = 0, my2 = 0, mar = 0;
    int myc = -1;
    if (tid < gc) {
      unsigned u = 0xFFFFFFFFu - (unsigned)v;
      myc = (int)(u >> 18);
      unsigned aidx = u & 0x3FFFFu;
      float4 b = decode_box(anc[aidx], reg[aidx]);
      mx1 = b.x; my1 = b.y; mx2 = b.z; my2 = b.w;
      mar = (b.z - b.x) * (b.w - b.y);
      bx1[tid] = b.x; by1[tid] = b.y; bx2[tid] = b.z; by2[tid] = b.w;
      ar[tid] = mar; scls[tid] = (unsigned short)myc;
      atomicOr(&classbit[myc * NW + (tid >> 6)], 1ULL << (tid & 63));
    }
    __syncthreads();

    // ---- per-thread suppressor bitmask: same-class predecessors with IoU>thr ----
    u64 sup[NW];
    #pragma unroll
    for (int w = 0; w < NW; ++w) sup[w] = 0ULL;
    if (tid < gc) {
      const int tw = tid >> 6;
      for (int w = 0; w <= tw; ++w) {
        u64 m = classbit[myc * NW + w];
        if (w == tw) m &= (tid & 63) ? ((1ULL << (tid & 63)) - 1ULL) : 0ULL;
        u64 acc = 0ULL;
        while (m) {
          int b = __ffsll(m) - 1;
          m &= m - 1ULL;
          int s = (w << 6) + b;
          if (iou_gt(mx1, my1, mx2, my2, mar, bx1[s], by1[s], bx2[s], by2[s], ar[s]))
            acc |= 1ULL << b;
        }
        sup[w] = acc;
      }
    }

    // ---- Jacobi fixpoint on kept bits (unique fixpoint == greedy keep set) ----
    if (tid < NW) {
      int lo = tid << 6;
      sK[tid] = (gc <= lo) ? 0ULL : ((gc - lo >= 64) ? ~0ULL : ((1ULL << (gc - lo)) - 1));
    }
    __syncthreads();
    for (int it = 0; it < KCAP; ++it) {
      if (tid == 0) s_chg = 0;
      __syncthreads();
      bool alive = (tid < gc);
      if (alive) {
        u64 r = 0ULL;
        #pragma unroll
        for (int w = 0; w < NW; ++w) r |= sup[w] & sK[w];
        alive = (r == 0ULL);
      }
      u64 nw = __ballot(alive);
      __syncthreads();                       // all sK reads complete before writes
      if (lane == 0 && nw != sK[wv]) { sK[wv] = nw; s_chg = 1; }
      __syncthreads();
      if (!s_chg) break;
    }
    if (tid == 0) {
      int kt = 0;
      for (int w = 0; w < NW; ++w) kt += __popcll(sK[w]);
      s_kept = kt;
    }
    __syncthreads();
    if (s_kept >= MDET || gc >= total) {
      if (tid < gc && ((sK[wv] >> lane) & 1ULL)) {
        int slot = __popcll(sK[wv] & ((1ULL << lane) - 1ULL));
        for (int w = 0; w < wv; ++w) slot += __popcll(sK[w]);
        if (slot < MDET) keptlist[slot] = tid;
      }
    } else {
      fallback = true;                       // need deeper list (never on this data)
    }
    __syncthreads();
  }

  if (fallback) {
    // ==== exact fallback: rebuild from classification (slow, never taken) ====
    const int totalNC = NA * NC;
    const int nv4 = totalNC >> 2;
    for (int t = tid; t < NBF; t += 1024) fhist[t] = 0u;
    __syncthreads();
    for (int q = tid; q < nv4; q += 1024) {
      float4 v4 = cls4[q];
      float vv[4] = {v4.x, v4.y, v4.z, v4.w};
      #pragma unroll
      for (int e = 0; e < 4; ++e)
        if (vv[e] > STHR) atomicAdd(&fhist[binf(__float_as_uint(vv[e]), SB)], 1u);
    }
    if (tid < totalNC - nv4 * 4) {
      float v = ((const float*)cls4)[nv4 * 4 + tid];
      if (v > STHR) atomicAdd(&fhist[binf(__float_as_uint(v), SB)], 1u);
    }
    __syncthreads();
    // threshold bin: strictly-above prefix with count <= K2CAP
    {
      int b0 = 2 * tid;
      int h0 = (b0 < NBF) ? (int)fhist[b0] : 0;
      int h1 = (b0 + 1 < NBF) ? (int)fhist[b0 + 1] : 0;
      int s = h0 + h1;
      int ss = s;
      for (int d = 1; d < 64; d <<= 1) {
        int v = __shfl_down(ss, d);
        if (lane + d < 64) ss += v;
      }
      if (lane == 0) wsum[wv] = ss;
      if (tid == 0) s_B2 = 0;
      __syncthreads();
      if (tid < 16) {
        int x = wsum[tid];
        for (int d = 1; d < 16; d <<= 1) {
          int v = __shfl_down(x, d);
          if (tid + d < 16) x += v;
        }
        wsuf[tid] = x;
      }
      __syncthreads();
      int suff = ss + ((wv < 15) ? wsuf[wv + 1] : 0);
      int suffn = suff - s;
      if (suff >= K2CAP && suffn < K2CAP) {
        int Bx = (suffn + h1 >= K2CAP) ? (b0 + 1) : b0;
        s_B2 = Bx + 1;
      }
      __syncthreads();
    }
    const int B2 = s_B2;
    for (int q = tid; q < nv4; q += 1024) {
      float4 v4 = cls4[q];
      float vv[4] = {v4.x, v4.y, v4.z, v4.w};
      #pragma unroll
      for (int e = 0; e < 4; ++e) {
        float v = vv[e];
        if (v > STHR && binf(__float_as_uint(v), SB) >= B2) {
          int f = q * 4 + e;
          int p = atomicAdd(&s_cnt2, 1);
          if (p < K2CAP) skey[p] = make_key(__float_as_uint(v), f % NC, f / NC);
        }
      }
    }
    if (tid < totalNC - nv4 * 4) {
      int f = nv4 * 4 + tid;
      float v = ((const float*)cls4)[f];
      if (v > STHR && binf(__float_as_uint(v), SB) >= B2) {
        int p = atomicAdd(&s_cnt2, 1);
        if (p < K2CAP) skey[p] = make_key(__float_as_uint(v), f % NC, f / NC);
      }
    }
    __syncthreads();
    const int gc2 = min(s_cnt2, K2CAP);
    int NS2 = 2;
    while (NS2 < gc2) NS2 <<= 1;
    for (int t = tid; t < NS2; t += 1024) if (t >= gc2) skey[t] = 0ULL;
    for (int k = 2; k <= NS2; k <<= 1) {
      for (int j = k >> 1; j > 0; j >>= 1) {
        __syncthreads();
        for (int i = tid; i < NS2; i += 1024) {
          int ixj = i ^ j;
          if (ixj > i) {
            u64 x = skey[i], y = skey[ixj];
            if (((i & k) == 0) ? (x < y) : (x > y)) { skey[i] = y; skey[ixj] = x; }
          }
        }
      }
    }
    __syncthreads();
    for (int t = tid; t < gc2; t += 1024) {
      u64 k = skey[t];
      unsigned u = 0xFFFFFFFFu - (unsigned)k;
      unsigned aidx = u & 0x3FFFFu;
      float4 b = decode_box(anc[aidx], reg[aidx]);
      bx1[t] = b.x; by1[t] = b.y; bx2[t] = b.z; by2[t] = b.w;
      ar[t] = (b.z - b.x) * (b.w - b.y);
      scls[t] = (unsigned short)(u >> 18);
      alv[t] = 1;
    }
    __syncthreads();
    if (tid < 64) {                          // exact wave-serial greedy, cap MDET
      int kept = 0;
      for (int i = 0; i < gc2 && kept < MDET; ++i) {
        int ci = (int)scls[i];
        int skip = 0;
        if (tid == 0) {                      // per-class PRE_K rank guard
          skip = (cls_seen[ci] >= 1024) ? 1 : 0;
          cls_seen[ci]++;
        }
        skip = __shfl(skip, 0);
        if (skip || !alv[i]) continue;
        if (tid == 0) keptlist[kept] = i;
        float x1 = bx1[i], y1 = by1[i], x2 = bx2[i], y2 = by2[i], ai = ar[i];
        for (int j = i + 1 + tid; j < gc2; j += 64)
          if (alv[j] && (int)scls[j] == ci &&
              iou_gt(x1, y1, x2, y2, ai, bx1[j], by1[j], bx2[j], by2[j], ar[j]))
            alv[j] = 0;
        ++kept;
      }
    }
    __syncthreads();
  }

  // ---- output: first MDET kept in sorted order (== global top-100 kept) ----
  if (tid < MDET) {
    int r = keptlist[tid];
    bool ok = (r >= 0);
    float b0 = -1.f, b1 = -1.f, b2 = -1.f, b3 = -1.f;
    float r0 = -1.f, r1 = -1.f, r2 = -1.f;
    float t0 = -1.f, t1 = -1.f, t2 = -1.f;
    float sc = -1.f, lab = -1.f;
    if (ok) {
      u64 key = skey[r];
      sc = __uint_as_float((unsigned)(key >> 32));
      unsigned u = 0xFFFFFFFFu - (unsigned)key;
      int c = (int)(u >> 18);
      unsigned aidx = u & 0x3FFFFu;
      float4 bb = decode_box(anc[aidx], reg[aidx]);
      b0 = bb.x; b1 = bb.y; b2 = bb.z; b3 = bb.w;
      lab = (float)c;
      r0 = rot[aidx * 3 + 0]; r1 = rot[aidx * 3 + 1]; r2 = rot[aidx * 3 + 2];
      float st = ta[aidx * 3 + 2];
      t0 = ta[aidx * 3 + 0] + td[aidx * 3 + 0] * st;
      t1 = ta[aidx * 3 + 1] + td[aidx * 3 + 1] * st;
      t2 = td[aidx * 3 + 2];
    }
    out[tid * 4 + 0] = b0; out[tid * 4 + 1] = b1;
    out[tid * 4 + 2] = b2; out[tid * 4 + 3] = b3;
    out[400 + tid] = sc;
    out[500 + tid] = lab;
    out[600 + tid * 3 + 0] = r0; out[600 + tid * 3 + 1] = r1; out[600 + tid * 3 + 2] = r2;
    out[900 + tid * 3 + 0] = t0; out[900 + tid * 3 + 1] = t1; out[900 + tid * 3 + 2] = t2;
  }
}

extern "C" void kernel_launch(void* const* d_in, const int* in_sizes, int n_in,
                              void* d_out, int out_size, void* d_ws, size_t ws_size,
                              hipStream_t stream) {
  const float* anchors        = (const float*)d_in[0];
  const float* regression     = (const float*)d_in[1];
  const float* classification = (const float*)d_in[2];
  const float* rotation       = (const float*)d_in[3];
  const float* tanch          = (const float*)d_in[4];
  const float* tdelta         = (const float*)d_in[5];
  float* out = (float*)d_out;

  char* ws = (char*)d_ws;
  size_t off = 0;
  auto alloc = [&](size_t bytes) -> void* {
    void* p = ws + off;
    off += (bytes + 255) & ~(size_t)255;
    return p;
  };
  int* gcnt   = (int*)alloc(4);
  int* totcnt = (int*)alloc(4);
  u64* gsel   = (u64*)alloc((size_t)KCAP * 8);

  k_zero<<<1, 64, 0, stream>>>(gcnt, totcnt);
  k_collect<<<2048, 256, 0, stream>>>((const float4*)classification, gsel, gcnt, totcnt);

  // dyn: skey 16K + boxes 40K + scls 4K + alv 2K + classbit 11.25K = ~73.3 KB
  hipFuncSetAttribute(reinterpret_cast<const void*>(k_top),
                      hipFuncAttributeMaxDynamicSharedMemorySize, 75776);
  k_top<<<1, 1024, 75776, stream>>>(gcnt, totcnt, gsel,
                                    (const float4*)classification,
                                    (const float4*)anchors, (const float4*)regression,
                                    tanch, tdelta, rotation, out);
}

// Round 16
// 32.674 us; speedup vs baseline: 3.9704x; 1.8550x over previous
//
#include <hip/hip_runtime.h>

#define NA 150381
#define NC 90
#define MDET 100
#define STHR 0.996f
#define T2 0.999985f  // E[#>T2]~203, segment cap 64 = 7.6 sigma
#define NTHR 0.5f
#define IMGF 896.0f
#define NBF 1056      // fallback histogram bins ((bits-SB)>>6 over [0.996,1))
#define KCAP 512      // gsel capacity (8 segments x 64)
#define NSEG 8
#define SEGC 64
#define NW 8          // KCAP/64 kept-words
#define K2CAP 2048    // fallback list capacity

typedef unsigned long long u64;

__device__ __forceinline__ int binf(unsigned bits, unsigned SB) {
  int b = (int)((bits - SB) >> 6);
  return b < NBF - 1 ? b : NBF - 1;
}
// single source of truth for box decode -> bit-identical everywhere
__device__ __forceinline__ float4 decode_box(float4 a, float4 r) {
  float cxa = (a.x + a.z) * 0.5f, cya = (a.y + a.w) * 0.5f;
  float wa = a.z - a.x, ha = a.w - a.y;
  float w = expf(r.w) * wa, h = expf(r.z) * ha;
  float cy = r.x * ha + cya, cx = r.y * wa + cxa;
  float4 b;
  b.x = fminf(fmaxf(cx - w * 0.5f, 0.f), IMGF);
  b.y = fminf(fmaxf(cy - h * 0.5f, 0.f), IMGF);
  b.z = fminf(fmaxf(cx + w * 0.5f, 0.f), IMGF);
  b.w = fminf(fmaxf(cy + h * 0.5f, 0.f), IMGF);
  return b;
}
__device__ __forceinline__ bool iou_gt(float x1, float y1, float x2, float y2, float a1,
                                       float u1, float v1, float u2, float v2, float a2) {
  float ix1 = fmaxf(x1, u1), iy1 = fmaxf(y1, v1);
  float ix2 = fminf(x2, u2), iy2 = fminf(y2, v2);
  float iw = fmaxf(ix2 - ix1, 0.f), ih = fmaxf(iy2 - iy1, 0.f);
  float inter = iw * ih;
  float uni = a1 + a2 - inter;
  return inter / fmaxf(uni, 1e-9f) > NTHR;
}
// key = score_bits<<32 | (0xFFFFFFFF - (c<<18 | anchor)): u64-desc order ==
// (score desc, class asc, anchor asc) == reference flat-index tie order.
__device__ __forceinline__ u64 make_key(unsigned bits, int c, int i) {
  return ((u64)bits << 32) |
         (u64)(0xFFFFFFFFu - (((unsigned)c << 18) | (unsigned)i));
}

// ---------------- zero segment counters + overflow flag + gsel ----------------
__global__ __launch_bounds__(512) void k_zero(int* __restrict__ gcnt8,
                                              int* __restrict__ ovf,
                                              u64* __restrict__ gsel) {
  int i = threadIdx.x;
  gsel[i] = 0ULL;                      // poison-proof: unfilled slots must be 0
  if (i < NSEG * 32) gcnt8[i] = 0;     // counters padded 128B apart
  if (i == 0) *ovf = 0;
}

// ---------------- stream 54MB: append >T2 to per-segment gsel ----------------
__global__ void k_collect(const float4* __restrict__ cls4, u64* __restrict__ gsel,
                          int* __restrict__ gcnt8, int* __restrict__ ovf) {
  const int total = NA * NC;
  const int nv4 = total >> 2;
  const int stride = gridDim.x * blockDim.x;
  const int seg = blockIdx.x & (NSEG - 1);
  for (int q = blockIdx.x * blockDim.x + threadIdx.x; q < nv4; q += stride) {
    float4 v4 = cls4[q];
    float vv[4] = {v4.x, v4.y, v4.z, v4.w};
    #pragma unroll
    for (int e = 0; e < 4; ++e) {
      float v = vv[e];
      if (v > T2) {
        int f = q * 4 + e;
        int p = atomicAdd(&gcnt8[seg * 32], 1);
        if (p < SEGC) gsel[seg * SEGC + p] = make_key(__float_as_uint(v), f % NC, f / NC);
        else *ovf = 1;
      }
    }
  }
  int g = blockIdx.x * blockDim.x + threadIdx.x;
  if (g < total - nv4 * 4) {
    int f = nv4 * 4 + g;
    float v = ((const float*)cls4)[f];
    if (v > T2) {
      int p = atomicAdd(&gcnt8[seg * 32], 1);
      if (p < SEGC) gsel[seg * SEGC + p] = make_key(__float_as_uint(v), f % NC, f / NC);
      else *ovf = 1;
    }
  }
}

// ---------------- one block: sort gsel, class-bitmap NMS fixpoint, output 100 ----
__global__ __launch_bounds__(512) void k_top(const int* __restrict__ gcnt8,
                                             const int* __restrict__ ovf,
                                             const u64* __restrict__ gsel,
                                             const float4* __restrict__ cls4,
                                             const float4* __restrict__ anc,
                                             const float4* __restrict__ reg,
                                             const float* __restrict__ ta,
                                             const float* __restrict__ td,
                                             const float* __restrict__ rot,
                                             float* __restrict__ out) {
  extern __shared__ u64 dyn[];
  u64* skey = dyn;                                     // [2048] 16 KB (fallback needs 2048)
  float* bx1 = (float*)(dyn + 2048);                   // 5 x [2048] 40 KB
  float* by1 = bx1 + 2048; float* bx2 = by1 + 2048;
  float* by2 = bx2 + 2048; float* ar  = by2 + 2048;
  unsigned short* scls = (unsigned short*)(ar + 2048); // [2048] 4 KB
  unsigned char*  alv  = (unsigned char*)(scls + 2048);// [2048] 2 KB
  u64* classbit = (u64*)(alv + 2048);                  // [NC][NW] 5.76 KB
  unsigned* fhist = (unsigned*)classbit;               // fallback overlay (1056 u32)
  __shared__ u64 sK[NW];
  __shared__ int keptlist[MDET];
  __shared__ int cls_seen[NC];
  __shared__ int wsum[8], wsuf[8];
  __shared__ int s_chg, s_cnt2, s_B2, s_kept, s_gc, s_fb;

  const int tid = threadIdx.x;
  const int wv = tid >> 6, lane = tid & 63;
  const unsigned SB = __float_as_uint(STHR);

  if (tid < NC) cls_seen[tid] = 0;
  if (tid < MDET) keptlist[tid] = -1;
  if (tid == 0) {
    int g = 0;
    for (int s = 0; s < NSEG; ++s) g += min(gcnt8[s * 32], SEGC);
    s_gc = g;
    s_fb = (*ovf != 0);
    s_cnt2 = 0; s_kept = 0;
  }
  for (int t = tid; t < NC * NW; t += 512) classbit[t] = 0ULL;
  __syncthreads();
  const int gc = s_gc;
  bool fallback = s_fb;

  if (!fallback) {
    // ---- element/thread bitonic sort of 512 slots (zeros sink to end) ----
    u64 v = gsel[tid];
    for (int k = 2; k <= 512; k <<= 1) {
      for (int j = k >> 1; j > 0; j >>= 1) {
        u64 p;
        if (j >= 64) {
          __syncthreads(); skey[tid] = v; __syncthreads();
          p = skey[tid ^ j];
        } else {
          p = __shfl_xor(v, j, 64);
        }
        u64 mx = (v >= p) ? v : p, mn = (v >= p) ? p : v;
        bool takeMax = (((tid & k) == 0) != ((tid & j) != 0));
        v = takeMax ? mx : mn;
      }
    }
    __syncthreads();
    skey[tid] = v;

    // ---- decode + stage boxes/class + class bitmap ----
    float mx1 = 0, my1 = 0, mx2 = 0, my2 = 0, mar = 0;
    int myc = -1;
    if (tid < gc) {
      unsigned u = 0xFFFFFFFFu - (unsigned)v;
      myc = (int)(u >> 18);
      unsigned aidx = u & 0x3FFFFu;
      float4 b = decode_box(anc[aidx], reg[aidx]);
      mx1 = b.x; my1 = b.y; mx2 = b.z; my2 = b.w;
      mar = (b.z - b.x) * (b.w - b.y);
      bx1[tid] = b.x; by1[tid] = b.y; bx2[tid] = b.z; by2[tid] = b.w;
      ar[tid] = mar; scls[tid] = (unsigned short)myc;
      atomicOr(&classbit[myc * NW + (tid >> 6)], 1ULL << (tid & 63));
    }
    __syncthreads();

    // ---- per-thread suppressor bitmask (fully unrolled: registers, no scratch) ----
    u64 sup[NW];
    const int tw = tid >> 6;
    const u64 lowmask = (tid & 63) ? ((1ULL << (tid & 63)) - 1ULL) : 0ULL;
    #pragma unroll
    for (int w = 0; w < NW; ++w) {
      u64 acc = 0ULL;
      if (tid < gc && w <= tw) {
        u64 m = classbit[myc * NW + w];
        if (w == tw) m &= lowmask;
        while (m) {
          int b = __ffsll(m) - 1;
          m &= m - 1ULL;
          int s = (w << 6) + b;
          if (iou_gt(mx1, my1, mx2, my2, mar, bx1[s], by1[s], bx2[s], by2[s], ar[s]))
            acc |= 1ULL << b;
        }
      }
      sup[w] = acc;
    }

    // ---- Jacobi fixpoint on kept bits (unique fixpoint == greedy keep set) ----
    if (tid < NW) {
      int lo = tid << 6;
      sK[tid] = (gc <= lo) ? 0ULL : ((gc - lo >= 64) ? ~0ULL : ((1ULL << (gc - lo)) - 1));
    }
    __syncthreads();
    for (int it = 0; it < KCAP; ++it) {
      if (tid == 0) s_chg = 0;
      __syncthreads();
      bool alive = (tid < gc);
      if (alive) {
        u64 r = 0ULL;
        #pragma unroll
        for (int w = 0; w < NW; ++w) r |= sup[w] & sK[w];
        alive = (r == 0ULL);
      }
      u64 nw = __ballot(alive);
      __syncthreads();                       // all sK reads complete before writes
      if (lane == 0 && nw != sK[wv]) { sK[wv] = nw; s_chg = 1; }
      __syncthreads();
      if (!s_chg) break;
    }
    if (tid == 0) {
      int kt = 0;
      for (int w = 0; w < NW; ++w) kt += __popcll(sK[w]);
      s_kept = kt;
    }
    __syncthreads();
    if (s_kept >= MDET) {
      if (tid < gc && ((sK[wv] >> lane) & 1ULL)) {
        int slot = __popcll(sK[wv] & ((1ULL << lane) - 1ULL));
        for (int w = 0; w < wv; ++w) slot += __popcll(sK[w]);
        if (slot < MDET) keptlist[slot] = tid;
      }
    } else {
      fallback = true;          // fewer than 100 kept among >T2: exact rescan
    }
    __syncthreads();
  }

  if (fallback) {
    // ==== exact fallback: rebuild from classification (slow, never taken) ====
    const int totalNC = NA * NC;
    const int nv4 = totalNC >> 2;
    for (int t = tid; t < NBF; t += 512) fhist[t] = 0u;
    __syncthreads();
    for (int q = tid; q < nv4; q += 512) {
      float4 v4 = cls4[q];
      float vv[4] = {v4.x, v4.y, v4.z, v4.w};
      #pragma unroll
      for (int e = 0; e < 4; ++e)
        if (vv[e] > STHR) atomicAdd(&fhist[binf(__float_as_uint(vv[e]), SB)], 1u);
    }
    if (tid < totalNC - nv4 * 4) {
      float v = ((const float*)cls4)[nv4 * 4 + tid];
      if (v > STHR) atomicAdd(&fhist[binf(__float_as_uint(v), SB)], 1u);
    }
    __syncthreads();
    // threshold bin: strictly-above prefix with count <= K2CAP (CH=3 covers 1056)
    {
      int clo = tid * 3, chi = min(clo + 3, NBF);
      int s = 0;
      for (int b = clo; b < chi; ++b) s += (int)fhist[b];
      int ss = s;
      for (int d = 1; d < 64; d <<= 1) {
        int v = __shfl_down(ss, d);
        if (lane + d < 64) ss += v;
      }
      if (lane == 0) wsum[wv] = ss;
      if (tid == 0) s_B2 = 0;
      __syncthreads();
      if (tid < 8) {
        int x = wsum[tid];
        for (int d = 1; d < 8; d <<= 1) {
          int v = __shfl_down(x, d);
          if (tid + d < 8) x += v;
        }
        wsuf[tid] = x;
      }
      __syncthreads();
      int suff = ss + ((wv < 7) ? wsuf[wv + 1] : 0);
      int suffn = suff - s;
      if (clo < NBF && suff >= K2CAP && suffn < K2CAP) {
        int after = suffn, Bx = clo;
        for (int b = chi - 1; b >= clo; --b) {
          after += (int)fhist[b];
          if (after >= K2CAP) { Bx = b; break; }
        }
        s_B2 = Bx + 1;
      }
      __syncthreads();
    }
    const int B2 = s_B2;
    for (int q = tid; q < nv4; q += 512) {
      float4 v4 = cls4[q];
      float vv[4] = {v4.x, v4.y, v4.z, v4.w};
      #pragma unroll
      for (int e = 0; e < 4; ++e) {
        float v = vv[e];
        if (v > STHR && binf(__float_as_uint(v), SB) >= B2) {
          int f = q * 4 + e;
          int p = atomicAdd(&s_cnt2, 1);
          if (p < K2CAP) skey[p] = make_key(__float_as_uint(v), f % NC, f / NC);
        }
      }
    }
    if (tid < totalNC - nv4 * 4) {
      int f = nv4 * 4 + tid;
      float v = ((const float*)cls4)[f];
      if (v > STHR && binf(__float_as_uint(v), SB) >= B2) {
        int p = atomicAdd(&s_cnt2, 1);
        if (p < K2CAP) skey[p] = make_key(__float_as_uint(v), f % NC, f / NC);
      }
    }
    __syncthreads();
    const int gc2 = min(s_cnt2, K2CAP);
    int NS2 = 2;
    while (NS2 < gc2) NS2 <<= 1;
    for (int t = tid; t < NS2; t += 512) if (t >= gc2) skey[t] = 0ULL;
    for (int k = 2; k <= NS2; k <<= 1) {
      for (int j = k >> 1; j > 0; j >>= 1) {
        __syncthreads();
        for (int i = tid; i < NS2; i += 512) {
          int ixj = i ^ j;
          if (ixj > i) {
            u64 x = skey[i], y = skey[ixj];
            if (((i & k) == 0) ? (x < y) : (x > y)) { skey[i] = y; skey[ixj] = x; }
          }
        }
      }
    }
    __syncthreads();
    for (int t = tid; t < gc2; t += 512) {
      u64 k = skey[t];
      unsigned u = 0xFFFFFFFFu - (unsigned)k;
      unsigned aidx = u & 0x3FFFFu;
      float4 b = decode_box(anc[aidx], reg[aidx]);
      bx1[t] = b.x; by1[t] = b.y; bx2[t] = b.z; by2[t] = b.w;
      ar[t] = (b.z - b.x) * (b.w - b.y);
      scls[t] = (unsigned short)(u >> 18);
      alv[t] = 1;
    }
    __syncthreads();
    if (tid < 64) {                          // exact wave-serial greedy, cap MDET
      int kept = 0;
      for (int i = 0; i < gc2 && kept < MDET; ++i) {
        int ci = (int)scls[i];
        int skip = 0;
        if (tid == 0) {                      // per-class PRE_K rank guard
          skip = (cls_seen[ci] >= 1024) ? 1 : 0;
          cls_seen[ci]++;
        }
        skip = __shfl(skip, 0);
        if (skip || !alv[i]) continue;
        if (tid == 0) keptlist[kept] = i;
        float x1 = bx1[i], y1 = by1[i], x2 = bx2[i], y2 = by2[i], ai = ar[i];
        for (int j = i + 1 + tid; j < gc2; j += 64)
          if (alv[j] && (int)scls[j] == ci &&
              iou_gt(x1, y1, x2, y2, ai, bx1[j], by1[j], bx2[j], by2[j], ar[j]))
            alv[j] = 0;
        ++kept;
      }
    }
    __syncthreads();
  }

  // ---- output: first MDET kept in sorted order (== global top-100 kept) ----
  if (tid < MDET) {
    int r = keptlist[tid];
    bool ok = (r >= 0);
    float b0 = -1.f, b1 = -1.f, b2 = -1.f, b3 = -1.f;
    float r0 = -1.f, r1 = -1.f, r2 = -1.f;
    float t0 = -1.f, t1 = -1.f, t2 = -1.f;
    float sc = -1.f, lab = -1.f;
    if (ok) {
      u64 key = skey[r];
      sc = __uint_as_float((unsigned)(key >> 32));
      unsigned u = 0xFFFFFFFFu - (unsigned)key;
      int c = (int)(u >> 18);
      unsigned aidx = u & 0x3FFFFu;
      float4 bb = decode_box(anc[aidx], reg[aidx]);
      b0 = bb.x; b1 = bb.y; b2 = bb.z; b3 = bb.w;
      lab = (float)c;
      r0 = rot[aidx * 3 + 0]; r1 = rot[aidx * 3 + 1]; r2 = rot[aidx * 3 + 2];
      float st = ta[aidx * 3 + 2];
      t0 = ta[aidx * 3 + 0] + td[aidx * 3 + 0] * st;
      t1 = ta[aidx * 3 + 1] + td[aidx * 3 + 1] * st;
      t2 = td[aidx * 3 + 2];
    }
    out[tid * 4 + 0] = b0; out[tid * 4 + 1] = b1;
    out[tid * 4 + 2] = b2; out[tid * 4 + 3] = b3;
    out[400 + tid] = sc;
    out[500 + tid] = lab;
    out[600 + tid * 3 + 0] = r0; out[600 + tid * 3 + 1] = r1; out[600 + tid * 3 + 2] = r2;
    out[900 + tid * 3 + 0] = t0; out[900 + tid * 3 + 1] = t1; out[900 + tid * 3 + 2] = t2;
  }
}

extern "C" void kernel_launch(void* const* d_in, const int* in_sizes, int n_in,
                              void* d_out, int out_size, void* d_ws, size_t ws_size,
                              hipStream_t stream) {
  const float* anchors        = (const float*)d_in[0];
  const float* regression     = (const float*)d_in[1];
  const float* classification = (const float*)d_in[2];
  const float* rotation       = (const float*)d_in[3];
  const float* tanch          = (const float*)d_in[4];
  const float* tdelta         = (const float*)d_in[5];
  float* out = (float*)d_out;

  char* ws = (char*)d_ws;
  size_t off = 0;
  auto alloc = [&](size_t bytes) -> void* {
    void* p = ws + off;
    off += (bytes + 255) & ~(size_t)255;
    return p;
  };
  int* gcnt8 = (int*)alloc(NSEG * 32 * 4);   // counters padded 128B apart
  int* ovf   = (int*)alloc(4);
  u64* gsel  = (u64*)alloc((size_t)KCAP * 8);

  k_zero<<<1, 512, 0, stream>>>(gcnt8, ovf, gsel);
  k_collect<<<2048, 256, 0, stream>>>((const float4*)classification, gsel, gcnt8, ovf);

  // dyn: skey 16K + boxes 40K + scls 4K + alv 2K + classbit 5.76K = ~67.7 KB
  hipFuncSetAttribute(reinterpret_cast<const void*>(k_top),
                      hipFuncAttributeMaxDynamicSharedMemorySize, 69632);
  k_top<<<1, 512, 69632, stream>>>(gcnt8, ovf, gsel,
                                   (const float4*)classification,
                                   (const float4*)anchors, (const float4*)regression,
                                   tanch, tdelta, rotation, out);
}

// Round 17
// 30.678 us; speedup vs baseline: 4.2287x; 1.0651x over previous
//
#include <hip/hip_runtime.h>

#define NA 150381
#define NC 90
#define MDET 100
#define STHR 0.996f
#define T2 0.999985f  // E[#>T2]~203, segment cap 64 = 7.6 sigma
#define NTHR 0.5f
#define IMGF 896.0f
#define NBF 1056      // fallback histogram bins ((bits-SB)>>6 over [0.996,1))
#define KCAP 512      // gsel capacity (8 segments x 64)
#define NSEG 8
#define SEGC 64
#define NW 8          // KCAP/64 kept-words
#define K2CAP 2048    // fallback list capacity

typedef unsigned long long u64;

__device__ __forceinline__ int binf(unsigned bits, unsigned SB) {
  int b = (int)((bits - SB) >> 6);
  return b < NBF - 1 ? b : NBF - 1;
}
// single source of truth for box decode -> bit-identical everywhere
__device__ __forceinline__ float4 decode_box(float4 a, float4 r) {
  float cxa = (a.x + a.z) * 0.5f, cya = (a.y + a.w) * 0.5f;
  float wa = a.z - a.x, ha = a.w - a.y;
  float w = expf(r.w) * wa, h = expf(r.z) * ha;
  float cy = r.x * ha + cya, cx = r.y * wa + cxa;
  float4 b;
  b.x = fminf(fmaxf(cx - w * 0.5f, 0.f), IMGF);
  b.y = fminf(fmaxf(cy - h * 0.5f, 0.f), IMGF);
  b.z = fminf(fmaxf(cx + w * 0.5f, 0.f), IMGF);
  b.w = fminf(fmaxf(cy + h * 0.5f, 0.f), IMGF);
  return b;
}
__device__ __forceinline__ bool iou_gt(float x1, float y1, float x2, float y2, float a1,
                                       float u1, float v1, float u2, float v2, float a2) {
  float ix1 = fmaxf(x1, u1), iy1 = fmaxf(y1, v1);
  float ix2 = fminf(x2, u2), iy2 = fminf(y2, v2);
  float iw = fmaxf(ix2 - ix1, 0.f), ih = fmaxf(iy2 - iy1, 0.f);
  float inter = iw * ih;
  float uni = a1 + a2 - inter;
  return inter / fmaxf(uni, 1e-9f) > NTHR;
}
// key = score_bits<<32 | (0xFFFFFFFF - (c<<18 | anchor)): u64-desc order ==
// (score desc, class asc, anchor asc) == reference flat-index tie order.
__device__ __forceinline__ u64 make_key(unsigned bits, int c, int i) {
  return ((u64)bits << 32) |
         (u64)(0xFFFFFFFFu - (((unsigned)c << 18) | (unsigned)i));
}

// ---------------- zero segment counters + overflow flag (gsel NOT zeroed:
// k_top only reads slots < cnt[seg], all written fresh each launch) ----------
__global__ __launch_bounds__(256) void k_zero(int* __restrict__ gcnt8,
                                              int* __restrict__ ovf) {
  int i = threadIdx.x;
  if (i < NSEG * 32) gcnt8[i] = 0;     // counters padded 128B apart
  if (i == 0) *ovf = 0;
}

// ---------------- stream 54MB: append >T2 to per-segment gsel ----------------
__global__ void k_collect(const float4* __restrict__ cls4, u64* __restrict__ gsel,
                          int* __restrict__ gcnt8, int* __restrict__ ovf) {
  const int total = NA * NC;
  const int nv4 = total >> 2;
  const int stride = gridDim.x * blockDim.x;
  const int seg = blockIdx.x & (NSEG - 1);
  for (int q = blockIdx.x * blockDim.x + threadIdx.x; q < nv4; q += stride) {
    float4 v4 = cls4[q];
    float vv[4] = {v4.x, v4.y, v4.z, v4.w};
    #pragma unroll
    for (int e = 0; e < 4; ++e) {
      float v = vv[e];
      if (v > T2) {
        int f = q * 4 + e;
        int p = atomicAdd(&gcnt8[seg * 32], 1);
        if (p < SEGC) gsel[seg * SEGC + p] = make_key(__float_as_uint(v), f % NC, f / NC);
        else *ovf = 1;
      }
    }
  }
  int g = blockIdx.x * blockDim.x + threadIdx.x;
  if (g < total - nv4 * 4) {
    int f = nv4 * 4 + g;
    float v = ((const float*)cls4)[f];
    if (v > T2) {
      int p = atomicAdd(&gcnt8[seg * 32], 1);
      if (p < SEGC) gsel[seg * SEGC + p] = make_key(__float_as_uint(v), f % NC, f / NC);
      else *ovf = 1;
    }
  }
}

// ---------------- one block: compact+sort gsel, class-bitmap NMS fixpoint ------
__global__ __launch_bounds__(512) void k_top(const int* __restrict__ gcnt8,
                                             const int* __restrict__ ovf,
                                             const u64* __restrict__ gsel,
                                             const float4* __restrict__ cls4,
                                             const float4* __restrict__ anc,
                                             const float4* __restrict__ reg,
                                             const float* __restrict__ ta,
                                             const float* __restrict__ td,
                                             const float* __restrict__ rot,
                                             float* __restrict__ out) {
  extern __shared__ u64 dyn[];
  u64* skey = dyn;                                     // [2048] 16 KB (fallback needs 2048)
  float* bx1 = (float*)(dyn + 2048);                   // 5 x [2048] 40 KB
  float* by1 = bx1 + 2048; float* bx2 = by1 + 2048;
  float* by2 = bx2 + 2048; float* ar  = by2 + 2048;
  unsigned short* scls = (unsigned short*)(ar + 2048); // [2048] 4 KB
  unsigned char*  alv  = (unsigned char*)(scls + 2048);// [2048] 2 KB
  u64* classbit = (u64*)(alv + 2048);                  // [NC][NW] 5.76 KB
  unsigned* fhist = (unsigned*)classbit;               // fallback overlay (1056 u32)
  __shared__ u64 sK[NW];
  __shared__ int keptlist[MDET];
  __shared__ int cls_seen[NC];
  __shared__ int s_cnt[NSEG], s_base[NSEG];
  __shared__ int wsum[8], wsuf[8];
  __shared__ int s_chg, s_cnt2, s_B2, s_kept, s_gc, s_fb;

  const int tid = threadIdx.x;
  const int wv = tid >> 6, lane = tid & 63;
  const unsigned SB = __float_as_uint(STHR);

  if (tid < NC) cls_seen[tid] = 0;
  if (tid < MDET) keptlist[tid] = -1;
  if (tid < NSEG) s_cnt[tid] = min(gcnt8[tid * 32], SEGC);
  if (tid == 0) { s_fb = (*ovf != 0); s_cnt2 = 0; s_kept = 0; }
  for (int t = tid; t < NC * NW; t += 512) classbit[t] = 0ULL;
  __syncthreads();
  if (tid == 0) {
    int b = 0;
    for (int s = 0; s < NSEG; ++s) { s_base[s] = b; b += s_cnt[s]; }
    s_gc = b;
  }
  __syncthreads();
  const int gc = s_gc;
  bool fallback = s_fb;

  if (!fallback) {
    // ---- compact per-segment valid slots into skey[0,gc), zero-pad to 512 ----
    const int seg = tid >> 6, slot = tid & 63;
    const bool val = slot < s_cnt[seg];
    u64 kv = val ? gsel[tid] : 0ULL;
    skey[tid] = 0ULL;
    __syncthreads();
    if (val) skey[s_base[seg] + slot] = kv;
    __syncthreads();
    u64 v = skey[tid];

    // ---- element/thread bitonic sort (NS=256 typical; 512 if gc>256) ----
    const int NS = (gc <= 256) ? 256 : 512;
    for (int k = 2; k <= NS; k <<= 1) {
      for (int j = k >> 1; j > 0; j >>= 1) {
        u64 p;
        if (j >= 64) {
          __syncthreads(); skey[tid] = v; __syncthreads();
          p = skey[tid ^ j];
        } else {
          p = __shfl_xor(v, j, 64);
        }
        u64 mx = (v >= p) ? v : p, mn = (v >= p) ? p : v;
        bool takeMax = (((tid & k) == 0) != ((tid & j) != 0));
        v = takeMax ? mx : mn;
      }
    }
    __syncthreads();
    skey[tid] = v;

    // ---- decode + stage boxes/class + class bitmap ----
    float mx1 = 0, my1 = 0, mx2 = 0, my2 = 0, mar = 0;
    int myc = -1;
    if (tid < gc) {
      unsigned u = 0xFFFFFFFFu - (unsigned)v;
      myc = (int)(u >> 18);
      unsigned aidx = u & 0x3FFFFu;
      float4 b = decode_box(anc[aidx], reg[aidx]);
      mx1 = b.x; my1 = b.y; mx2 = b.z; my2 = b.w;
      mar = (b.z - b.x) * (b.w - b.y);
      bx1[tid] = b.x; by1[tid] = b.y; bx2[tid] = b.z; by2[tid] = b.w;
      ar[tid] = mar; scls[tid] = (unsigned short)myc;
      atomicOr(&classbit[myc * NW + (tid >> 6)], 1ULL << (tid & 63));
    }
    __syncthreads();

    // ---- per-thread suppressor bitmask (fully unrolled: registers, no scratch) ----
    u64 sup[NW];
    const int tw = tid >> 6;
    const u64 lowmask = (tid & 63) ? ((1ULL << (tid & 63)) - 1ULL) : 0ULL;
    #pragma unroll
    for (int w = 0; w < NW; ++w) {
      u64 acc = 0ULL;
      if (tid < gc && w <= tw) {
        u64 m = classbit[myc * NW + w];
        if (w == tw) m &= lowmask;
        while (m) {
          int b = __ffsll(m) - 1;
          m &= m - 1ULL;
          int s = (w << 6) + b;
          if (iou_gt(mx1, my1, mx2, my2, mar, bx1[s], by1[s], bx2[s], by2[s], ar[s]))
            acc |= 1ULL << b;
        }
      }
      sup[w] = acc;
    }

    // ---- Jacobi fixpoint on kept bits (unique fixpoint == greedy keep set) ----
    if (tid < NW) {
      int lo = tid << 6;
      sK[tid] = (gc <= lo) ? 0ULL : ((gc - lo >= 64) ? ~0ULL : ((1ULL << (gc - lo)) - 1));
    }
    __syncthreads();
    for (int it = 0; it < KCAP; ++it) {
      if (tid == 0) s_chg = 0;
      __syncthreads();
      bool alive = (tid < gc);
      if (alive) {
        u64 r = 0ULL;
        #pragma unroll
        for (int w = 0; w < NW; ++w) r |= sup[w] & sK[w];
        alive = (r == 0ULL);
      }
      u64 nw = __ballot(alive);
      __syncthreads();                       // all sK reads complete before writes
      if (lane == 0 && nw != sK[wv]) { sK[wv] = nw; s_chg = 1; }
      __syncthreads();
      if (!s_chg) break;
    }
    if (tid == 0) {
      int kt = 0;
      for (int w = 0; w < NW; ++w) kt += __popcll(sK[w]);
      s_kept = kt;
    }
    __syncthreads();
    if (s_kept >= MDET) {
      if (tid < gc && ((sK[wv] >> lane) & 1ULL)) {
        int slot2 = __popcll(sK[wv] & ((1ULL << lane) - 1ULL));
        for (int w = 0; w < wv; ++w) slot2 += __popcll(sK[w]);
        if (slot2 < MDET) keptlist[slot2] = tid;
      }
    } else {
      fallback = true;          // fewer than 100 kept among >T2: exact rescan
    }
    __syncthreads();
  }

  if (fallback) {
    // ==== exact fallback: rebuild from classification (slow, never taken) ====
    const int totalNC = NA * NC;
    const int nv4 = totalNC >> 2;
    for (int t = tid; t < NBF; t += 512) fhist[t] = 0u;
    __syncthreads();
    for (int q = tid; q < nv4; q += 512) {
      float4 v4 = cls4[q];
      float vv[4] = {v4.x, v4.y, v4.z, v4.w};
      #pragma unroll
      for (int e = 0; e < 4; ++e)
        if (vv[e] > STHR) atomicAdd(&fhist[binf(__float_as_uint(vv[e]), SB)], 1u);
    }
    if (tid < totalNC - nv4 * 4) {
      float v = ((const float*)cls4)[nv4 * 4 + tid];
      if (v > STHR) atomicAdd(&fhist[binf(__float_as_uint(v), SB)], 1u);
    }
    __syncthreads();
    // threshold bin: strictly-above prefix with count <= K2CAP (CH=3 covers 1056)
    {
      int clo = tid * 3, chi = min(clo + 3, NBF);
      int s = 0;
      for (int b = clo; b < chi; ++b) s += (int)fhist[b];
      int ss = s;
      for (int d = 1; d < 64; d <<= 1) {
        int v = __shfl_down(ss, d);
        if (lane + d < 64) ss += v;
      }
      if (lane == 0) wsum[wv] = ss;
      if (tid == 0) s_B2 = 0;
      __syncthreads();
      if (tid < 8) {
        int x = wsum[tid];
        for (int d = 1; d < 8; d <<= 1) {
          int v = __shfl_down(x, d);
          if (tid + d < 8) x += v;
        }
        wsuf[tid] = x;
      }
      __syncthreads();
      int suff = ss + ((wv < 7) ? wsuf[wv + 1] : 0);
      int suffn = suff - s;
      if (clo < NBF && suff >= K2CAP && suffn < K2CAP) {
        int after = suffn, Bx = clo;
        for (int b = chi - 1; b >= clo; --b) {
          after += (int)fhist[b];
          if (after >= K2CAP) { Bx = b; break; }
        }
        s_B2 = Bx + 1;
      }
      __syncthreads();
    }
    const int B2 = s_B2;
    for (int q = tid; q < nv4; q += 512) {
      float4 v4 = cls4[q];
      float vv[4] = {v4.x, v4.y, v4.z, v4.w};
      #pragma unroll
      for (int e = 0; e < 4; ++e) {
        float v = vv[e];
        if (v > STHR && binf(__float_as_uint(v), SB) >= B2) {
          int f = q * 4 + e;
          int p = atomicAdd(&s_cnt2, 1);
          if (p < K2CAP) skey[p] = make_key(__float_as_uint(v), f % NC, f / NC);
        }
      }
    }
    if (tid < totalNC - nv4 * 4) {
      int f = nv4 * 4 + tid;
      float v = ((const float*)cls4)[f];
      if (v > STHR && binf(__float_as_uint(v), SB) >= B2) {
        int p = atomicAdd(&s_cnt2, 1);
        if (p < K2CAP) skey[p] = make_key(__float_as_uint(v), f % NC, f / NC);
      }
    }
    __syncthreads();
    const int gc2 = min(s_cnt2, K2CAP);
    int NS2 = 2;
    while (NS2 < gc2) NS2 <<= 1;
    for (int t = tid; t < NS2; t += 512) if (t >= gc2) skey[t] = 0ULL;
    for (int k = 2; k <= NS2; k <<= 1) {
      for (int j = k >> 1; j > 0; j >>= 1) {
        __syncthreads();
        for (int i = tid; i < NS2; i += 512) {
          int ixj = i ^ j;
          if (ixj > i) {
            u64 x = skey[i], y = skey[ixj];
            if (((i & k) == 0) ? (x < y) : (x > y)) { skey[i] = y; skey[ixj] = x; }
          }
        }
      }
    }
    __syncthreads();
    for (int t = tid; t < gc2; t += 512) {
      u64 k = skey[t];
      unsigned u = 0xFFFFFFFFu - (unsigned)k;
      unsigned aidx = u & 0x3FFFFu;
      float4 b = decode_box(anc[aidx], reg[aidx]);
      bx1[t] = b.x; by1[t] = b.y; bx2[t] = b.z; by2[t] = b.w;
      ar[t] = (b.z - b.x) * (b.w - b.y);
      scls[t] = (unsigned short)(u >> 18);
      alv[t] = 1;
    }
    __syncthreads();
    if (tid < 64) {                          // exact wave-serial greedy, cap MDET
      int kept = 0;
      for (int i = 0; i < gc2 && kept < MDET; ++i) {
        int ci = (int)scls[i];
        int skip = 0;
        if (tid == 0) {                      // per-class PRE_K rank guard
          skip = (cls_seen[ci] >= 1024) ? 1 : 0;
          cls_seen[ci]++;
        }
        skip = __shfl(skip, 0);
        if (skip || !alv[i]) continue;
        if (tid == 0) keptlist[kept] = i;
        float x1 = bx1[i], y1 = by1[i], x2 = bx2[i], y2 = by2[i], ai = ar[i];
        for (int j = i + 1 + tid; j < gc2; j += 64)
          if (alv[j] && (int)scls[j] == ci &&
              iou_gt(x1, y1, x2, y2, ai, bx1[j], by1[j], bx2[j], by2[j], ar[j]))
            alv[j] = 0;
        ++kept;
      }
    }
    __syncthreads();
  }

  // ---- output: first MDET kept in sorted order (== global top-100 kept) ----
  if (tid < MDET) {
    int r = keptlist[tid];
    bool ok = (r >= 0);
    float b0 = -1.f, b1 = -1.f, b2 = -1.f, b3 = -1.f;
    float r0 = -1.f, r1 = -1.f, r2 = -1.f;
    float t0 = -1.f, t1 = -1.f, t2 = -1.f;
    float sc = -1.f, lab = -1.f;
    if (ok) {
      u64 key = skey[r];
      sc = __uint_as_float((unsigned)(key >> 32));
      unsigned u = 0xFFFFFFFFu - (unsigned)key;
      int c = (int)(u >> 18);
      unsigned aidx = u & 0x3FFFFu;
      float4 bb = decode_box(anc[aidx], reg[aidx]);
      b0 = bb.x; b1 = bb.y; b2 = bb.z; b3 = bb.w;
      lab = (float)c;
      r0 = rot[aidx * 3 + 0]; r1 = rot[aidx * 3 + 1]; r2 = rot[aidx * 3 + 2];
      float st = ta[aidx * 3 + 2];
      t0 = ta[aidx * 3 + 0] + td[aidx * 3 + 0] * st;
      t1 = ta[aidx * 3 + 1] + td[aidx * 3 + 1] * st;
      t2 = td[aidx * 3 + 2];
    }
    out[tid * 4 + 0] = b0; out[tid * 4 + 1] = b1;
    out[tid * 4 + 2] = b2; out[tid * 4 + 3] = b3;
    out[400 + tid] = sc;
    out[500 + tid] = lab;
    out[600 + tid * 3 + 0] = r0; out[600 + tid * 3 + 1] = r1; out[600 + tid * 3 + 2] = r2;
    out[900 + tid * 3 + 0] = t0; out[900 + tid * 3 + 1] = t1; out[900 + tid * 3 + 2] = t2;
  }
}

extern "C" void kernel_launch(void* const* d_in, const int* in_sizes, int n_in,
                              void* d_out, int out_size, void* d_ws, size_t ws_size,
                              hipStream_t stream) {
  const float* anchors        = (const float*)d_in[0];
  const float* regression     = (const float*)d_in[1];
  const float* classification = (const float*)d_in[2];
  const float* rotation       = (const float*)d_in[3];
  const float* tanch          = (const float*)d_in[4];
  const float* tdelta         = (const float*)d_in[5];
  float* out = (float*)d_out;

  char* ws = (char*)d_ws;
  size_t off = 0;
  auto alloc = [&](size_t bytes) -> void* {
    void* p = ws + off;
    off += (bytes + 255) & ~(size_t)255;
    return p;
  };
  int* gcnt8 = (int*)alloc(NSEG * 32 * 4);   // counters padded 128B apart
  int* ovf   = (int*)alloc(4);
  u64* gsel  = (u64*)alloc((size_t)KCAP * 8);

  k_zero<<<1, 256, 0, stream>>>(gcnt8, ovf);
  k_collect<<<2048, 256, 0, stream>>>((const float4*)classification, gsel, gcnt8, ovf);

  // dyn: skey 16K + boxes 40K + scls 4K + alv 2K + classbit 5.76K = ~67.7 KB
  hipFuncSetAttribute(reinterpret_cast<const void*>(k_top),
                      hipFuncAttributeMaxDynamicSharedMemorySize, 69632);
  k_top<<<1, 512, 69632, stream>>>(gcnt8, ovf, gsel,
                                   (const float4*)classification,
                                   (const float4*)anchors, (const float4*)regression,
                                   tanch, tdelta, rotation, out);
}